// Round 1
// baseline (3437.458 us; speedup 1.0000x reference)
//
#include <hip/hip_runtime.h>

#define N_NODES 100000
#define N_EDGES 600000

// ---------------------------------------------------------------------------
// Degree accumulation: deg_s[senders[e]] += 1 ; deg_r[receivers[e]] += 1
// ---------------------------------------------------------------------------
__global__ void deg_kernel(const int* __restrict__ senders,
                           const int* __restrict__ receivers,
                           float* __restrict__ deg_s, float* __restrict__ deg_r,
                           int nE) {
    int e = blockIdx.x * blockDim.x + threadIdx.x;
    if (e < nE) {
        atomicAdd(&deg_s[senders[e]], 1.0f);
        atomicAdd(&deg_r[receivers[e]], 1.0f);
    }
}

// v <- rsqrt(max(v,1))  (applied to both degree arrays, laid out contiguously)
__global__ void rsqrt_kernel(float* __restrict__ v, int n) {
    int i = blockIdx.x * blockDim.x + threadIdx.x;
    if (i < n) v[i] = rsqrtf(fmaxf(v[i], 1.0f));
}

// ---------------------------------------------------------------------------
// y[row] = softmax(relu(x[row]*scale_in @ W + b)) * inv_out[row]
// One wave per row; lane owns output cols (2*lane, 2*lane+1). W in LDS (64KB).
// x-row broadcast via __shfl from registers (no block sync in the row loop).
// ---------------------------------------------------------------------------
template<bool SCALE_IN>
__global__ __launch_bounds__(512)
void gc_dense(const float* __restrict__ x, const float* __restrict__ W,
              const float* __restrict__ bias, const float* __restrict__ inv_in,
              const float* __restrict__ inv_out, float* __restrict__ y, int n) {
    __shared__ float wlds[128 * 128];
    {
        const float4* W4 = (const float4*)W;
        float4* wl4 = (float4*)wlds;
        for (int i = threadIdx.x; i < 128 * 128 / 4; i += blockDim.x) wl4[i] = W4[i];
    }
    __syncthreads();
    const int lane = threadIdx.x & 63;
    const int wave = threadIdx.x >> 6;
    const int gw = blockIdx.x * (blockDim.x >> 6) + wave;
    const int nw = gridDim.x * (blockDim.x >> 6);
    const float bA = bias[2 * lane];
    const float bB = bias[2 * lane + 1];
    for (int row = gw; row < n; row += nw) {
        const float sin_ = SCALE_IN ? inv_in[row] : 1.0f;
        const float xlo = x[(size_t)row * 128 + lane] * sin_;
        const float xhi = x[(size_t)row * 128 + 64 + lane] * sin_;
        float acc0 = bA, acc1 = bB;
        #pragma unroll 8
        for (int k = 0; k < 64; ++k) {
            const float a = __shfl(xlo, k);
            const float c = __shfl(xhi, k);
            const float2 w0 = *(const float2*)&wlds[k * 128 + 2 * lane];
            const float2 w1 = *(const float2*)&wlds[(k + 64) * 128 + 2 * lane];
            acc0 += a * w0.x + c * w1.x;
            acc1 += a * w0.y + c * w1.y;
        }
        // relu
        const float v0 = fmaxf(acc0, 0.0f), v1 = fmaxf(acc1, 0.0f);
        // softmax over the 128 values held across the wave
        float m = fmaxf(v0, v1);
        #pragma unroll
        for (int off = 32; off; off >>= 1) m = fmaxf(m, __shfl_xor(m, off));
        const float e0 = __expf(v0 - m);
        const float e1 = __expf(v1 - m);
        float s = e0 + e1;
        #pragma unroll
        for (int off = 32; off; off >>= 1) s += __shfl_xor(s, off);
        const float sc = inv_out[row] / s;
        float2 o; o.x = e0 * sc; o.y = e1 * sc;
        *(float2*)&y[(size_t)row * 128 + 2 * lane] = o;
    }
}

// ---------------------------------------------------------------------------
// dst[receivers[e]] += src[senders[e]]  (dst pre-zeroed). 32 threads/edge,
// each handles 4 contiguous floats: float4 gather + 4 atomicAdds.
// ---------------------------------------------------------------------------
__global__ void scatter_kernel(const float* __restrict__ src, float* __restrict__ dst,
                               const int* __restrict__ senders,
                               const int* __restrict__ receivers, int nE) {
    int t = blockIdx.x * blockDim.x + threadIdx.x;
    int e = t >> 5;
    if (e < nE) {
        int p = (t & 31) << 2;
        int s = senders[e];
        int r = receivers[e];
        const float4 v = *(const float4*)&src[(size_t)s * 128 + p];
        float* d = &dst[(size_t)r * 128 + p];
        atomicAdd(d + 0, v.x);
        atomicAdd(d + 1, v.y);
        atomicAdd(d + 2, v.z);
        atomicAdd(d + 3, v.w);
    }
}

// ---------------------------------------------------------------------------
// out[row] = concat(h[row]*inv_r[row], nodes[row]) @ W + b   (W: [256,64])
// One wave per row; lane owns one output col. W in LDS (64KB).
// ---------------------------------------------------------------------------
__global__ __launch_bounds__(512)
void head_kernel(const float* __restrict__ h, const float* __restrict__ inv_r,
                 const float* __restrict__ nodes, const float* __restrict__ W,
                 const float* __restrict__ bias, float* __restrict__ out, int n) {
    __shared__ float wlds[256 * 64];
    {
        const float4* W4 = (const float4*)W;
        float4* wl4 = (float4*)wlds;
        for (int i = threadIdx.x; i < 256 * 64 / 4; i += blockDim.x) wl4[i] = W4[i];
    }
    __syncthreads();
    const int lane = threadIdx.x & 63;
    const int wave = threadIdx.x >> 6;
    const int gw = blockIdx.x * (blockDim.x >> 6) + wave;
    const int nw = gridDim.x * (blockDim.x >> 6);
    const float b = bias[lane];
    for (int row = gw; row < n; row += nw) {
        const float ir = inv_r[row];
        const float x0 = h[(size_t)row * 128 + lane] * ir;
        const float x1 = h[(size_t)row * 128 + 64 + lane] * ir;
        const float x2 = nodes[(size_t)row * 128 + lane];
        const float x3 = nodes[(size_t)row * 128 + 64 + lane];
        float acc = b;
        #pragma unroll 8
        for (int k = 0; k < 64; ++k) {
            const float a = __shfl(x0, k);
            const float c = __shfl(x1, k);
            const float d = __shfl(x2, k);
            const float e = __shfl(x3, k);
            acc += a * wlds[k * 64 + lane];
            acc += c * wlds[(k + 64) * 64 + lane];
            acc += d * wlds[(k + 128) * 64 + lane];
            acc += e * wlds[(k + 192) * 64 + lane];
        }
        out[(size_t)row * 64 + lane] = acc;
    }
}

extern "C" void kernel_launch(void* const* d_in, const int* in_sizes, int n_in,
                              void* d_out, int out_size, void* d_ws, size_t ws_size,
                              hipStream_t stream) {
    const float* nodes    = (const float*)d_in[0];
    const int*   senders   = (const int*)d_in[1];
    const int*   receivers = (const int*)d_in[2];
    const float* W0  = (const float*)d_in[3];
    const float* b0  = (const float*)d_in[4];
    const float* W1  = (const float*)d_in[5];
    const float* b1  = (const float*)d_in[6];
    const float* Wmu = (const float*)d_in[7];
    const float* bmu = (const float*)d_in[8];
    const float* Wls = (const float*)d_in[9];
    const float* bls = (const float*)d_in[10];
    float* out = (float*)d_out;

    const int N = N_NODES;
    const int E = N_EDGES;

    // workspace layout (floats): inv_s[N] | inv_r[N] | buf0[N*128] | buf1[N*128]
    float* inv_s = (float*)d_ws;
    float* inv_r = inv_s + N;
    float* buf0  = inv_r + N;
    float* buf1  = buf0 + (size_t)N * 128;

    // degrees -> rsqrt factors
    hipMemsetAsync(inv_s, 0, 2ull * N * sizeof(float), stream);
    deg_kernel<<<(E + 255) / 256, 256, 0, stream>>>(senders, receivers, inv_s, inv_r, E);
    rsqrt_kernel<<<(2 * N + 255) / 256, 256, 0, stream>>>(inv_s, 2 * N);

    // layer 1: dense+softmax (scaled by inv_s), scatter to buf1
    gc_dense<false><<<512, 512, 0, stream>>>(nodes, W0, b0, nullptr, inv_s, buf0, N);
    hipMemsetAsync(buf1, 0, (size_t)N * 128 * sizeof(float), stream);
    scatter_kernel<<<(E * 32 + 255) / 256, 256, 0, stream>>>(buf0, buf1, senders, receivers, E);

    // layer 2: input scaled by inv_r, dense+softmax scaled by inv_s, scatter
    gc_dense<true><<<512, 512, 0, stream>>>(buf1, W1, b1, inv_r, inv_s, buf0, N);
    hipMemsetAsync(buf1, 0, (size_t)N * 128 * sizeof(float), stream);
    scatter_kernel<<<(E * 32 + 255) / 256, 256, 0, stream>>>(buf0, buf1, senders, receivers, E);

    // heads: mu then logsig2 (output = [mu | logsig2] flat)
    head_kernel<<<512, 512, 0, stream>>>(buf1, inv_r, nodes, Wmu, bmu, out, N);
    head_kernel<<<512, 512, 0, stream>>>(buf1, inv_r, nodes, Wls, bls, out + (size_t)N * 64, N);
}

// Round 2
// 1600.057 us; speedup vs baseline: 2.1483x; 2.1483x over previous
//
#include <hip/hip_runtime.h>

#define N_NODES 100000
#define N_EDGES 600000

// ---------------------------------------------------------------------------
// Int histogram of senders and receivers.
// ---------------------------------------------------------------------------
__global__ void hist_kernel(const int* __restrict__ senders,
                            const int* __restrict__ receivers,
                            int* __restrict__ cnt_s, int* __restrict__ cnt_r, int nE) {
    int e = blockIdx.x * blockDim.x + threadIdx.x;
    if (e < nE) {
        atomicAdd(&cnt_s[senders[e]], 1);
        atomicAdd(&cnt_r[receivers[e]], 1);
    }
}

__global__ void inv_kernel(const int* __restrict__ cs, const int* __restrict__ cr,
                           float* __restrict__ inv_s, float* __restrict__ inv_r, int n) {
    int i = blockIdx.x * blockDim.x + threadIdx.x;
    if (i < n) {
        inv_s[i] = rsqrtf(fmaxf((float)cs[i], 1.0f));
        inv_r[i] = rsqrtf(fmaxf((float)cr[i], 1.0f));
    }
}

// ---------------------------------------------------------------------------
// Exclusive scan of cnt (length n) -> offs, 3-kernel hierarchical.
// ---------------------------------------------------------------------------
__global__ void scan1_kernel(const int* __restrict__ cnt, int* __restrict__ offs,
                             int* __restrict__ bsum, int n) {
    __shared__ int a[256], b[256];
    const int t = threadIdx.x;
    const int i = blockIdx.x * 256 + t;
    const int v = (i < n) ? cnt[i] : 0;
    a[t] = v;
    __syncthreads();
    int* pin = a; int* pout = b;
    #pragma unroll
    for (int off = 1; off < 256; off <<= 1) {
        pout[t] = pin[t] + ((t >= off) ? pin[t - off] : 0);
        __syncthreads();
        int* tmp = pin; pin = pout; pout = tmp;
    }
    if (i < n) offs[i] = pin[t] - v;           // exclusive
    if (t == 255) bsum[blockIdx.x] = pin[255]; // block total
}

__global__ void scan2_kernel(int* __restrict__ bsum, int nb) {
    __shared__ int a[512], b[512];
    const int t = threadIdx.x;
    const int v = (t < nb) ? bsum[t] : 0;
    a[t] = v;
    __syncthreads();
    int* pin = a; int* pout = b;
    #pragma unroll
    for (int off = 1; off < 512; off <<= 1) {
        pout[t] = pin[t] + ((t >= off) ? pin[t - off] : 0);
        __syncthreads();
        int* tmp = pin; pin = pout; pout = tmp;
    }
    if (t < nb) bsum[t] = pin[t] - v;          // exclusive
}

__global__ void scan3_kernel(int* __restrict__ offs, const int* __restrict__ bsum,
                             int* __restrict__ cursor, int n, int total) {
    int i = blockIdx.x * 256 + threadIdx.x;
    if (i < n) {
        int o = offs[i] + bsum[i >> 8];
        offs[i] = o;
        cursor[i] = o;
    }
    if (i == 0) offs[n] = total;
}

// ---------------------------------------------------------------------------
// Reorder: sorted-by-receiver sender list.
// ---------------------------------------------------------------------------
__global__ void reorder_kernel(const int* __restrict__ senders,
                               const int* __restrict__ receivers,
                               int* __restrict__ cursor, int* __restrict__ srt, int nE) {
    int e = blockIdx.x * blockDim.x + threadIdx.x;
    if (e < nE) {
        int pos = atomicAdd(&cursor[receivers[e]], 1);
        srt[pos] = senders[e];
    }
}

// ---------------------------------------------------------------------------
// dst[r] = sum over incoming edges of src[sender]. One wave per receiver,
// lane owns float2 (cols 2l,2l+1). Writes every row (zeros for deg-0).
// ---------------------------------------------------------------------------
__global__ __launch_bounds__(256)
void aggregate_kernel(const float* __restrict__ src, float* __restrict__ dst,
                      const int* __restrict__ offs, const int* __restrict__ srt, int n) {
    const int lane = threadIdx.x & 63;
    const int wave = threadIdx.x >> 6;
    const int gw = blockIdx.x * 4 + wave;
    const int nw = gridDim.x * 4;
    const float2* s2 = (const float2*)src;
    float2* d2 = (float2*)dst;
    for (int r = gw; r < n; r += nw) {
        const int beg = offs[r], end = offs[r + 1];
        float ax = 0.0f, ay = 0.0f;
        for (int j = beg; j < end; ++j) {
            const int s = srt[j];
            const float2 v = s2[(size_t)s * 64 + lane];
            ax += v.x; ay += v.y;
        }
        float2 o; o.x = ax; o.y = ay;
        d2[(size_t)r * 64 + lane] = o;
    }
}

// ---------------------------------------------------------------------------
// y[row] = softmax(relu(x[row]*scale_in @ W + b)) * inv_out[row]
// One wave per row; lane owns output cols (2*lane, 2*lane+1). W in LDS (64KB).
// ---------------------------------------------------------------------------
template<bool SCALE_IN>
__global__ __launch_bounds__(512)
void gc_dense(const float* __restrict__ x, const float* __restrict__ W,
              const float* __restrict__ bias, const float* __restrict__ inv_in,
              const float* __restrict__ inv_out, float* __restrict__ y, int n) {
    __shared__ float wlds[128 * 128];
    {
        const float4* W4 = (const float4*)W;
        float4* wl4 = (float4*)wlds;
        for (int i = threadIdx.x; i < 128 * 128 / 4; i += blockDim.x) wl4[i] = W4[i];
    }
    __syncthreads();
    const int lane = threadIdx.x & 63;
    const int wave = threadIdx.x >> 6;
    const int gw = blockIdx.x * (blockDim.x >> 6) + wave;
    const int nw = gridDim.x * (blockDim.x >> 6);
    const float bA = bias[2 * lane];
    const float bB = bias[2 * lane + 1];
    for (int row = gw; row < n; row += nw) {
        const float sin_ = SCALE_IN ? inv_in[row] : 1.0f;
        const float xlo = x[(size_t)row * 128 + lane] * sin_;
        const float xhi = x[(size_t)row * 128 + 64 + lane] * sin_;
        float acc0 = bA, acc1 = bB;
        #pragma unroll 8
        for (int k = 0; k < 64; ++k) {
            const float a = __shfl(xlo, k);
            const float c = __shfl(xhi, k);
            const float2 w0 = *(const float2*)&wlds[k * 128 + 2 * lane];
            const float2 w1 = *(const float2*)&wlds[(k + 64) * 128 + 2 * lane];
            acc0 += a * w0.x + c * w1.x;
            acc1 += a * w0.y + c * w1.y;
        }
        const float v0 = fmaxf(acc0, 0.0f), v1 = fmaxf(acc1, 0.0f);
        float m = fmaxf(v0, v1);
        #pragma unroll
        for (int off = 32; off; off >>= 1) m = fmaxf(m, __shfl_xor(m, off));
        const float e0 = __expf(v0 - m);
        const float e1 = __expf(v1 - m);
        float s = e0 + e1;
        #pragma unroll
        for (int off = 32; off; off >>= 1) s += __shfl_xor(s, off);
        const float sc = inv_out[row] / s;
        float2 o; o.x = e0 * sc; o.y = e1 * sc;
        *(float2*)&y[(size_t)row * 128 + 2 * lane] = o;
    }
}

// ---------------------------------------------------------------------------
// out[row] = concat(h[row]*inv_r[row], nodes[row]) @ W + b   (W: [256,64])
// ---------------------------------------------------------------------------
__global__ __launch_bounds__(512)
void head_kernel(const float* __restrict__ h, const float* __restrict__ inv_r,
                 const float* __restrict__ nodes, const float* __restrict__ W,
                 const float* __restrict__ bias, float* __restrict__ out, int n) {
    __shared__ float wlds[256 * 64];
    {
        const float4* W4 = (const float4*)W;
        float4* wl4 = (float4*)wlds;
        for (int i = threadIdx.x; i < 256 * 64 / 4; i += blockDim.x) wl4[i] = W4[i];
    }
    __syncthreads();
    const int lane = threadIdx.x & 63;
    const int wave = threadIdx.x >> 6;
    const int gw = blockIdx.x * (blockDim.x >> 6) + wave;
    const int nw = gridDim.x * (blockDim.x >> 6);
    const float b = bias[lane];
    for (int row = gw; row < n; row += nw) {
        const float ir = inv_r[row];
        const float x0 = h[(size_t)row * 128 + lane] * ir;
        const float x1 = h[(size_t)row * 128 + 64 + lane] * ir;
        const float x2 = nodes[(size_t)row * 128 + lane];
        const float x3 = nodes[(size_t)row * 128 + 64 + lane];
        float acc = b;
        #pragma unroll 8
        for (int k = 0; k < 64; ++k) {
            const float a = __shfl(x0, k);
            const float c = __shfl(x1, k);
            const float d = __shfl(x2, k);
            const float e = __shfl(x3, k);
            acc += a * wlds[k * 64 + lane];
            acc += c * wlds[(k + 64) * 64 + lane];
            acc += d * wlds[(k + 128) * 64 + lane];
            acc += e * wlds[(k + 192) * 64 + lane];
        }
        out[(size_t)row * 64 + lane] = acc;
    }
}

extern "C" void kernel_launch(void* const* d_in, const int* in_sizes, int n_in,
                              void* d_out, int out_size, void* d_ws, size_t ws_size,
                              hipStream_t stream) {
    const float* nodes     = (const float*)d_in[0];
    const int*   senders   = (const int*)d_in[1];
    const int*   receivers = (const int*)d_in[2];
    const float* W0  = (const float*)d_in[3];
    const float* b0  = (const float*)d_in[4];
    const float* W1  = (const float*)d_in[5];
    const float* b1  = (const float*)d_in[6];
    const float* Wmu = (const float*)d_in[7];
    const float* bmu = (const float*)d_in[8];
    const float* Wls = (const float*)d_in[9];
    const float* bls = (const float*)d_in[10];
    float* out = (float*)d_out;

    const int N = N_NODES;
    const int E = N_EDGES;
    const int NB = (N + 255) / 256;  // 391 scan blocks

    // Persistent workspace: inv_s[N] | inv_r[N] | buf0[N*128] | buf1[N*128]
    float* inv_s = (float*)d_ws;
    float* inv_r = inv_s + N;
    float* buf0  = inv_r + N;
    float* buf1  = buf0 + (size_t)N * 128;

    // Sort metadata lives in d_out (scratch until the heads write it at the end):
    // offs[N+1] | srt[E]   (700001 ints = 2.8 MB << 51.2 MB)
    int* offs = (int*)d_out;
    int* srt  = offs + (N + 1);

    // Setup-only temporaries alias buf0 (dead before gc_dense writes buf0):
    // cnt_s[N] | cnt_r[N] | cursor[N] | bsum[NB]
    int* cnt_s  = (int*)buf0;
    int* cnt_r  = cnt_s + N;
    int* cursor = cnt_r + N;
    int* bsum   = cursor + N;

    // --- degree histograms + rsqrt factors ---
    hipMemsetAsync(cnt_s, 0, 2ull * N * sizeof(int), stream);
    hist_kernel<<<(E + 255) / 256, 256, 0, stream>>>(senders, receivers, cnt_s, cnt_r, E);
    inv_kernel<<<(N + 255) / 256, 256, 0, stream>>>(cnt_s, cnt_r, inv_s, inv_r, N);

    // --- counting sort of edges by receiver ---
    scan1_kernel<<<NB, 256, 0, stream>>>(cnt_r, offs, bsum, N);
    scan2_kernel<<<1, 512, 0, stream>>>(bsum, NB);
    scan3_kernel<<<NB, 256, 0, stream>>>(offs, bsum, cursor, N, E);
    reorder_kernel<<<(E + 255) / 256, 256, 0, stream>>>(senders, receivers, cursor, srt, E);

    // --- layer 1 ---
    gc_dense<false><<<512, 512, 0, stream>>>(nodes, W0, b0, nullptr, inv_s, buf0, N);
    aggregate_kernel<<<1024, 256, 0, stream>>>(buf0, buf1, offs, srt, N);

    // --- layer 2 (input scaled by inv_r inside gc_dense) ---
    gc_dense<true><<<512, 512, 0, stream>>>(buf1, W1, b1, inv_r, inv_s, buf0, N);
    aggregate_kernel<<<1024, 256, 0, stream>>>(buf0, buf1, offs, srt, N);

    // --- heads: out = [mu | logsig2] flat (overwrites the sort scratch) ---
    head_kernel<<<512, 512, 0, stream>>>(buf1, inv_r, nodes, Wmu, bmu, out, N);
    head_kernel<<<512, 512, 0, stream>>>(buf1, inv_r, nodes, Wls, bls, out + (size_t)N * 64, N);
}

// Round 3
// 532.342 us; speedup vs baseline: 6.4572x; 3.0057x over previous
//
#include <hip/hip_runtime.h>

#define N_NODES 100000
#define N_EDGES 600000

typedef __attribute__((ext_vector_type(8))) short short8;   // 8 bf16 (4 VGPRs)
typedef __attribute__((ext_vector_type(4))) float f32x4;    // MFMA accumulator

// round-to-nearest-even f32 -> bf16 bits, packed pair
__device__ inline unsigned bf16pack2(float x, float y) {
    unsigned ux = __float_as_uint(x), uy = __float_as_uint(y);
    ux = (ux + 0x7FFFu + ((ux >> 16) & 1u)) >> 16;
    uy = (uy + 0x7FFFu + ((uy >> 16) & 1u)) >> 16;
    return ux | (uy << 16);
}

// ---------------------------------------------------------------------------
// Weight prep: transposed bf16 copies. Wt[n][k] = bf16(W[k][n]).
// ---------------------------------------------------------------------------
__global__ void prep_wt128(const float* __restrict__ W, unsigned short* __restrict__ Wt) {
    int i = blockIdx.x * 256 + threadIdx.x;          // 128x128
    if (i < 128 * 128) {
        int nn = i >> 7, k = i & 127;
        unsigned u = __float_as_uint(W[k * 128 + nn]);
        Wt[i] = (unsigned short)((u + 0x7FFFu + ((u >> 16) & 1u)) >> 16);
    }
}
__global__ void prep_wht(const float* __restrict__ Wmu, const float* __restrict__ Wls,
                         unsigned short* __restrict__ Wt) {
    int i = blockIdx.x * 256 + threadIdx.x;          // 128 n x 256 k
    if (i < 128 * 256) {
        int nn = i >> 8, k = i & 255;
        float v = (nn < 64) ? Wmu[k * 64 + nn] : Wls[k * 64 + (nn - 64)];
        unsigned u = __float_as_uint(v);
        Wt[i] = (unsigned short)((u + 0x7FFFu + ((u >> 16) & 1u)) >> 16);
    }
}

// ---------------------------------------------------------------------------
// Histogram / degree factors / scan / reorder (counting sort by receiver)
// ---------------------------------------------------------------------------
__global__ void hist_kernel(const int* __restrict__ senders,
                            const int* __restrict__ receivers,
                            int* __restrict__ cnt_s, int* __restrict__ cnt_r, int nE) {
    int e = blockIdx.x * blockDim.x + threadIdx.x;
    if (e < nE) {
        atomicAdd(&cnt_s[senders[e]], 1);
        atomicAdd(&cnt_r[receivers[e]], 1);
    }
}

__global__ void inv_kernel(const int* __restrict__ cs, const int* __restrict__ cr,
                           float* __restrict__ inv_s, float* __restrict__ inv_r, int n) {
    int i = blockIdx.x * blockDim.x + threadIdx.x;
    if (i < n) {
        inv_s[i] = rsqrtf(fmaxf((float)cs[i], 1.0f));
        inv_r[i] = rsqrtf(fmaxf((float)cr[i], 1.0f));
    }
}

__global__ void scan1_kernel(const int* __restrict__ cnt, int* __restrict__ offs,
                             int* __restrict__ bsum, int n) {
    __shared__ int a[256], b[256];
    const int t = threadIdx.x;
    const int i = blockIdx.x * 256 + t;
    const int v = (i < n) ? cnt[i] : 0;
    a[t] = v;
    __syncthreads();
    int* pin = a; int* pout = b;
    #pragma unroll
    for (int off = 1; off < 256; off <<= 1) {
        pout[t] = pin[t] + ((t >= off) ? pin[t - off] : 0);
        __syncthreads();
        int* tmp = pin; pin = pout; pout = tmp;
    }
    if (i < n) offs[i] = pin[t] - v;
    if (t == 255) bsum[blockIdx.x] = pin[255];
}

__global__ void scan2_kernel(int* __restrict__ bsum, int nb) {
    __shared__ int a[512], b[512];
    const int t = threadIdx.x;
    const int v = (t < nb) ? bsum[t] : 0;
    a[t] = v;
    __syncthreads();
    int* pin = a; int* pout = b;
    #pragma unroll
    for (int off = 1; off < 512; off <<= 1) {
        pout[t] = pin[t] + ((t >= off) ? pin[t - off] : 0);
        __syncthreads();
        int* tmp = pin; pin = pout; pout = tmp;
    }
    if (t < nb) bsum[t] = pin[t] - v;
}

__global__ void scan3_kernel(int* __restrict__ offs, const int* __restrict__ bsum,
                             int* __restrict__ cursor, int n, int total) {
    int i = blockIdx.x * 256 + threadIdx.x;
    if (i < n) {
        int o = offs[i] + bsum[i >> 8];
        offs[i] = o;
        cursor[i] = o;
    }
    if (i == 0) offs[n] = total;
}

__global__ void reorder_kernel(const int* __restrict__ senders,
                               const int* __restrict__ receivers,
                               int* __restrict__ cursor, int* __restrict__ srt, int nE) {
    int e = blockIdx.x * blockDim.x + threadIdx.x;
    if (e < nE) {
        int pos = atomicAdd(&cursor[receivers[e]], 1);
        srt[pos] = senders[e];
    }
}

// ---------------------------------------------------------------------------
// dst[r] = sum of src[sender] over incoming edges (sorted list). Wave/receiver.
// ---------------------------------------------------------------------------
__global__ __launch_bounds__(256)
void aggregate_kernel(const float* __restrict__ src, float* __restrict__ dst,
                      const int* __restrict__ offs, const int* __restrict__ srt, int n) {
    const int lane = threadIdx.x & 63;
    const int wave = threadIdx.x >> 6;
    const int gw = blockIdx.x * 4 + wave;
    const int nw = gridDim.x * 4;
    const float2* s2 = (const float2*)src;
    float2* d2 = (float2*)dst;
    for (int r = gw; r < n; r += nw) {
        const int beg = offs[r], end = offs[r + 1];
        float ax = 0.0f, ay = 0.0f;
        for (int j = beg; j < end; ++j) {
            const int s = srt[j];
            const float2 v = s2[(size_t)s * 64 + lane];
            ax += v.x; ay += v.y;
        }
        float2 o; o.x = ax; o.y = ay;
        d2[(size_t)r * 64 + lane] = o;
    }
}

// ---------------------------------------------------------------------------
// MFMA graph-conv layer: y = softmax(relu((x*inv_in) @ W + b)) * inv_out
// Block: 256 thr, 64-row tile. X staged bf16 in LDS (padded 136). Wt[n][k]
// bf16 read from global (L2-resident). Wave w owns cols [w*32, w*32+32).
// mfma_f32_16x16x32_bf16: A[m=lane&15][k=(lane>>4)*8+j], C col=lane&15,
// row=(lane>>4)*4+reg.
// ---------------------------------------------------------------------------
template<bool SCALE_IN>
__global__ __launch_bounds__(256)
void gc_mfma(const float* __restrict__ x, const unsigned short* __restrict__ Wt,
             const float* __restrict__ bias, const float* __restrict__ inv_in,
             const float* __restrict__ inv_out, float* __restrict__ y, int nrows) {
    __shared__ unsigned short Xl[64 * 136];
    __shared__ float sred0[4][64];
    __shared__ float sred1[4][64];
    const int row0 = blockIdx.x * 64;
    // stage X (f32 -> bf16, optional row scale)
    for (int c = threadIdx.x; c < 64 * 32; c += 256) {
        int r = c >> 5, c4 = c & 31;
        int grow = row0 + r;
        float4 v = make_float4(0.f, 0.f, 0.f, 0.f);
        if (grow < nrows) {
            v = *(const float4*)&x[(size_t)grow * 128 + c4 * 4];
            if (SCALE_IN) {
                float s = inv_in[grow];
                v.x *= s; v.y *= s; v.z *= s; v.w *= s;
            }
        }
        *(uint2*)&Xl[r * 136 + c4 * 4] = make_uint2(bf16pack2(v.x, v.y), bf16pack2(v.z, v.w));
    }
    __syncthreads();

    const int lane = threadIdx.x & 63;
    const int w = threadIdx.x >> 6;
    const int q = lane >> 4;
    const int l16 = lane & 15;

    // preload B fragments (4 k-steps x 2 n-tiles) from global Wt
    short8 bf[4][2];
    #pragma unroll
    for (int k0 = 0; k0 < 4; ++k0)
        #pragma unroll
        for (int nt = 0; nt < 2; ++nt) {
            int ncol = w * 32 + nt * 16 + l16;
            bf[k0][nt] = *(const short8*)&Wt[ncol * 128 + k0 * 32 + q * 8];
        }

    f32x4 acc[4][2] = {};
    #pragma unroll
    for (int k0 = 0; k0 < 4; ++k0) {
        #pragma unroll
        for (int m = 0; m < 4; ++m) {
            short8 a = *(const short8*)&Xl[(m * 16 + l16) * 136 + k0 * 32 + q * 8];
            acc[m][0] = __builtin_amdgcn_mfma_f32_16x16x32_bf16(a, bf[k0][0], acc[m][0], 0, 0, 0);
            acc[m][1] = __builtin_amdgcn_mfma_f32_16x16x32_bf16(a, bf[k0][1], acc[m][1], 0, 0, 0);
        }
    }

    // epilogue: bias -> relu -> softmax(row over 128 cols) -> *inv_out
    const float bv0 = bias[w * 32 + l16];
    const float bv1 = bias[w * 32 + 16 + l16];
    float v[4][2][4];
    #pragma unroll
    for (int m = 0; m < 4; ++m)
        #pragma unroll
        for (int r = 0; r < 4; ++r) {
            v[m][0][r] = fmaxf(acc[m][0][r] + bv0, 0.0f);
            v[m][1][r] = fmaxf(acc[m][1][r] + bv1, 0.0f);
        }
    // wave-local row max over its 32 cols
    float t[4][4];
    #pragma unroll
    for (int m = 0; m < 4; ++m)
        #pragma unroll
        for (int r = 0; r < 4; ++r)
            t[m][r] = fmaxf(v[m][0][r], v[m][1][r]);
    #pragma unroll
    for (int off = 1; off < 16; off <<= 1)
        #pragma unroll
        for (int m = 0; m < 4; ++m)
            #pragma unroll
            for (int r = 0; r < 4; ++r)
                t[m][r] = fmaxf(t[m][r], __shfl_xor(t[m][r], off));
    if (l16 == 0) {
        #pragma unroll
        for (int m = 0; m < 4; ++m)
            #pragma unroll
            for (int r = 0; r < 4; ++r)
                sred0[w][m * 16 + q * 4 + r] = t[m][r];
    }
    __syncthreads();
    float M[4][4];
    #pragma unroll
    for (int m = 0; m < 4; ++m)
        #pragma unroll
        for (int r = 0; r < 4; ++r) {
            int row = m * 16 + q * 4 + r;
            M[m][r] = fmaxf(fmaxf(sred0[0][row], sred0[1][row]),
                            fmaxf(sred0[2][row], sred0[3][row]));
        }
    float s[4][4];
    #pragma unroll
    for (int m = 0; m < 4; ++m)
        #pragma unroll
        for (int r = 0; r < 4; ++r) {
            float e0 = __expf(v[m][0][r] - M[m][r]);
            float e1 = __expf(v[m][1][r] - M[m][r]);
            v[m][0][r] = e0; v[m][1][r] = e1;
            s[m][r] = e0 + e1;
        }
    #pragma unroll
    for (int off = 1; off < 16; off <<= 1)
        #pragma unroll
        for (int m = 0; m < 4; ++m)
            #pragma unroll
            for (int r = 0; r < 4; ++r)
                s[m][r] += __shfl_xor(s[m][r], off);
    if (l16 == 0) {
        #pragma unroll
        for (int m = 0; m < 4; ++m)
            #pragma unroll
            for (int r = 0; r < 4; ++r)
                sred1[w][m * 16 + q * 4 + r] = s[m][r];
    }
    __syncthreads();
    #pragma unroll
    for (int m = 0; m < 4; ++m)
        #pragma unroll
        for (int r = 0; r < 4; ++r) {
            int row = m * 16 + q * 4 + r;
            int grow = row0 + row;
            if (grow < nrows) {
                float S = sred1[0][row] + sred1[1][row] + sred1[2][row] + sred1[3][row];
                float sc = inv_out[grow] / S;
                y[(size_t)grow * 128 + w * 32 + l16]      = v[m][0][r] * sc;
                y[(size_t)grow * 128 + w * 32 + 16 + l16] = v[m][1][r] * sc;
            }
        }
}

// ---------------------------------------------------------------------------
// Fused heads: X = concat(h*inv_r, nodes) [64 rows x 256 k] staged bf16,
// Wht[n][k] n<64 -> mu cols, n>=64 -> ls cols. Waves 0,1 -> mu; 2,3 -> ls.
// ---------------------------------------------------------------------------
__global__ __launch_bounds__(256)
void head_mfma(const float* __restrict__ h, const float* __restrict__ inv_r,
               const float* __restrict__ nodes, const unsigned short* __restrict__ Wt,
               const float* __restrict__ bmu, const float* __restrict__ bls,
               float* __restrict__ out, int nrows) {
    __shared__ unsigned short Xl[64 * 264];
    const int row0 = blockIdx.x * 64;
    for (int c = threadIdx.x; c < 64 * 64; c += 256) {
        int r = c >> 6, c4 = c & 63;
        int grow = row0 + r;
        float4 v = make_float4(0.f, 0.f, 0.f, 0.f);
        if (grow < nrows) {
            if (c4 < 32) {
                v = *(const float4*)&h[(size_t)grow * 128 + c4 * 4];
                float s = inv_r[grow];
                v.x *= s; v.y *= s; v.z *= s; v.w *= s;
            } else {
                v = *(const float4*)&nodes[(size_t)grow * 128 + (c4 - 32) * 4];
            }
        }
        *(uint2*)&Xl[r * 264 + c4 * 4] = make_uint2(bf16pack2(v.x, v.y), bf16pack2(v.z, v.w));
    }
    __syncthreads();

    const int lane = threadIdx.x & 63;
    const int w = threadIdx.x >> 6;
    const int q = lane >> 4;
    const int l16 = lane & 15;

    short8 bf[8][2];
    #pragma unroll
    for (int k0 = 0; k0 < 8; ++k0)
        #pragma unroll
        for (int nt = 0; nt < 2; ++nt) {
            int ncol = w * 32 + nt * 16 + l16;
            bf[k0][nt] = *(const short8*)&Wt[ncol * 256 + k0 * 32 + q * 8];
        }

    f32x4 acc[4][2] = {};
    #pragma unroll
    for (int k0 = 0; k0 < 8; ++k0) {
        #pragma unroll
        for (int m = 0; m < 4; ++m) {
            short8 a = *(const short8*)&Xl[(m * 16 + l16) * 264 + k0 * 32 + q * 8];
            acc[m][0] = __builtin_amdgcn_mfma_f32_16x16x32_bf16(a, bf[k0][0], acc[m][0], 0, 0, 0);
            acc[m][1] = __builtin_amdgcn_mfma_f32_16x16x32_bf16(a, bf[k0][1], acc[m][1], 0, 0, 0);
        }
    }

    const float* bb = (w < 2) ? bmu : bls;
    float* ob = (w < 2) ? out : out + (size_t)nrows * 64;
    const int c0 = (w & 1) * 32 + l16;
    const int c1 = c0 + 16;
    const float b0v = bb[c0], b1v = bb[c1];
    #pragma unroll
    for (int m = 0; m < 4; ++m)
        #pragma unroll
        for (int r = 0; r < 4; ++r) {
            int grow = row0 + m * 16 + q * 4 + r;
            if (grow < nrows) {
                ob[(size_t)grow * 64 + c0] = acc[m][0][r] + b0v;
                ob[(size_t)grow * 64 + c1] = acc[m][1][r] + b1v;
            }
        }
}

extern "C" void kernel_launch(void* const* d_in, const int* in_sizes, int n_in,
                              void* d_out, int out_size, void* d_ws, size_t ws_size,
                              hipStream_t stream) {
    const float* nodes     = (const float*)d_in[0];
    const int*   senders   = (const int*)d_in[1];
    const int*   receivers = (const int*)d_in[2];
    const float* W0  = (const float*)d_in[3];
    const float* b0  = (const float*)d_in[4];
    const float* W1  = (const float*)d_in[5];
    const float* b1  = (const float*)d_in[6];
    const float* Wmu = (const float*)d_in[7];
    const float* bmu = (const float*)d_in[8];
    const float* Wls = (const float*)d_in[9];
    const float* bls = (const float*)d_in[10];
    float* out = (float*)d_out;

    const int N = N_NODES;
    const int E = N_EDGES;
    const int NB = (N + 255) / 256;      // scan blocks
    const int NT = (N + 63) / 64;        // 64-row GEMM tiles

    // ws: inv_s[N] | inv_r[N] | buf0[N*128] | buf1[N*128] | w0t | w1t | wht
    float* inv_s = (float*)d_ws;
    float* inv_r = inv_s + N;
    float* buf0  = inv_r + N;
    float* buf1  = buf0 + (size_t)N * 128;
    unsigned short* w0t = (unsigned short*)(buf1 + (size_t)N * 128);
    unsigned short* w1t = w0t + 128 * 128;
    unsigned short* wht = w1t + 128 * 128;

    // sort metadata in d_out (scratch until heads write it): offs[N+1] | srt[E]
    int* offs = (int*)d_out;
    int* srt  = offs + (N + 1);

    // setup-only temps alias buf0 (dead before layer-1 writes buf0)
    int* cnt_s  = (int*)buf0;
    int* cnt_r  = cnt_s + N;
    int* cursor = cnt_r + N;
    int* bsum   = cursor + N;

    // --- weight prep (bf16 transposed) ---
    prep_wt128<<<64, 256, 0, stream>>>(W0, w0t);
    prep_wt128<<<64, 256, 0, stream>>>(W1, w1t);
    prep_wht<<<128, 256, 0, stream>>>(Wmu, Wls, wht);

    // --- degrees + rsqrt factors ---
    hipMemsetAsync(cnt_s, 0, 2ull * N * sizeof(int), stream);
    hist_kernel<<<(E + 255) / 256, 256, 0, stream>>>(senders, receivers, cnt_s, cnt_r, E);
    inv_kernel<<<(N + 255) / 256, 256, 0, stream>>>(cnt_s, cnt_r, inv_s, inv_r, N);

    // --- counting sort of edges by receiver ---
    scan1_kernel<<<NB, 256, 0, stream>>>(cnt_r, offs, bsum, N);
    scan2_kernel<<<1, 512, 0, stream>>>(bsum, NB);
    scan3_kernel<<<NB, 256, 0, stream>>>(offs, bsum, cursor, N, E);
    reorder_kernel<<<(E + 255) / 256, 256, 0, stream>>>(senders, receivers, cursor, srt, E);

    // --- layer 1 ---
    gc_mfma<false><<<NT, 256, 0, stream>>>(nodes, w0t, b0, nullptr, inv_s, buf0, N);
    aggregate_kernel<<<1024, 256, 0, stream>>>(buf0, buf1, offs, srt, N);

    // --- layer 2 ---
    gc_mfma<true><<<NT, 256, 0, stream>>>(buf1, w1t, b1, inv_r, inv_s, buf0, N);
    aggregate_kernel<<<1024, 256, 0, stream>>>(buf0, buf1, offs, srt, N);

    // --- fused heads: out = [mu | logsig2] ---
    head_mfma<<<NT, 256, 0, stream>>>(buf1, inv_r, nodes, wht, bmu, bls, out, N);
}

// Round 4
// 402.347 us; speedup vs baseline: 8.5435x; 1.3231x over previous
//
#include <hip/hip_runtime.h>

#define N_NODES 100000
#define N_EDGES 600000

typedef __attribute__((ext_vector_type(8))) short short8;   // 8 bf16 (4 VGPRs)
typedef __attribute__((ext_vector_type(4))) float f32x4;    // MFMA accumulator

// round-to-nearest-even f32 -> bf16
__device__ inline unsigned short bf16r(float x) {
    unsigned u = __float_as_uint(x);
    return (unsigned short)((u + 0x7FFFu + ((u >> 16) & 1u)) >> 16);
}
__device__ inline unsigned bf16pack2(float x, float y) {
    unsigned ux = __float_as_uint(x), uy = __float_as_uint(y);
    ux = (ux + 0x7FFFu + ((ux >> 16) & 1u)) >> 16;
    uy = (uy + 0x7FFFu + ((uy >> 16) & 1u)) >> 16;
    return ux | (uy << 16);
}

// ---------------------------------------------------------------------------
// Weight prep: transposed bf16 copies. Wt[n][k] = bf16(W[k][n]).
// ---------------------------------------------------------------------------
__global__ void prep_wt128(const float* __restrict__ W, unsigned short* __restrict__ Wt) {
    int i = blockIdx.x * 256 + threadIdx.x;          // 128x128
    if (i < 128 * 128) {
        int nn = i >> 7, k = i & 127;
        Wt[i] = bf16r(W[k * 128 + nn]);
    }
}
__global__ void prep_wht(const float* __restrict__ Wmu, const float* __restrict__ Wls,
                         unsigned short* __restrict__ Wt) {
    int i = blockIdx.x * 256 + threadIdx.x;          // 128 n x 256 k
    if (i < 128 * 256) {
        int nn = i >> 8, k = i & 255;
        float v = (nn < 64) ? Wmu[k * 64 + nn] : Wls[k * 64 + (nn - 64)];
        Wt[i] = bf16r(v);
    }
}

// ---------------------------------------------------------------------------
// Histogram / scan / reorder (counting sort of edges by receiver)
// ---------------------------------------------------------------------------
__global__ void hist_kernel(const int* __restrict__ senders,
                            const int* __restrict__ receivers,
                            int* __restrict__ cnt_s, int* __restrict__ cnt_r, int nE) {
    int e = blockIdx.x * blockDim.x + threadIdx.x;
    if (e < nE) {
        atomicAdd(&cnt_s[senders[e]], 1);
        atomicAdd(&cnt_r[receivers[e]], 1);
    }
}

__global__ void scan1_kernel(const int* __restrict__ cnt, int* __restrict__ offs,
                             int* __restrict__ bsum, int n) {
    __shared__ int a[256], b[256];
    const int t = threadIdx.x;
    const int i = blockIdx.x * 256 + t;
    const int v = (i < n) ? cnt[i] : 0;
    a[t] = v;
    __syncthreads();
    int* pin = a; int* pout = b;
    #pragma unroll
    for (int off = 1; off < 256; off <<= 1) {
        pout[t] = pin[t] + ((t >= off) ? pin[t - off] : 0);
        __syncthreads();
        int* tmp = pin; pin = pout; pout = tmp;
    }
    if (i < n) offs[i] = pin[t] - v;
    if (t == 255) bsum[blockIdx.x] = pin[255];
}

__global__ void scan2_kernel(int* __restrict__ bsum, int nb) {
    __shared__ int a[512], b[512];
    const int t = threadIdx.x;
    const int v = (t < nb) ? bsum[t] : 0;
    a[t] = v;
    __syncthreads();
    int* pin = a; int* pout = b;
    #pragma unroll
    for (int off = 1; off < 512; off <<= 1) {
        pout[t] = pin[t] + ((t >= off) ? pin[t - off] : 0);
        __syncthreads();
        int* tmp = pin; pin = pout; pout = tmp;
    }
    if (t < nb) bsum[t] = pin[t] - v;
}

// finalize offsets + cursor + rsqrt degree factors (fused)
__global__ void scan3_kernel(int* __restrict__ offs, const int* __restrict__ bsum,
                             int* __restrict__ cursor,
                             const int* __restrict__ cs, const int* __restrict__ cr,
                             float* __restrict__ inv_s, float* __restrict__ inv_r,
                             int n, int total) {
    int i = blockIdx.x * 256 + threadIdx.x;
    if (i < n) {
        int o = offs[i] + bsum[i >> 8];
        offs[i] = o;
        cursor[i] = o;
        inv_s[i] = rsqrtf(fmaxf((float)cs[i], 1.0f));
        inv_r[i] = rsqrtf(fmaxf((float)cr[i], 1.0f));
    }
    if (i == 0) offs[n] = total;
}

__global__ void reorder_kernel(const int* __restrict__ senders,
                               const int* __restrict__ receivers,
                               int* __restrict__ cursor, int* __restrict__ srt, int nE) {
    int e = blockIdx.x * blockDim.x + threadIdx.x;
    if (e < nE) {
        int pos = atomicAdd(&cursor[receivers[e]], 1);
        srt[pos] = senders[e];
    }
}

// ---------------------------------------------------------------------------
// dst[r] = bf16( inv_r[r] * sum over incoming edges of src[sender] )
// src/dst are bf16 rows (128 cols = 64 uints). One wave per receiver; lane
// owns cols (2l, 2l+1). Edge indices vector-loaded 64 at a time and
// broadcast via shfl (no per-edge scalar index load on the critical path).
// ---------------------------------------------------------------------------
__global__ __launch_bounds__(256)
void aggregate_kernel(const unsigned* __restrict__ src, unsigned* __restrict__ dst,
                      const int* __restrict__ offs, const int* __restrict__ srt,
                      const float* __restrict__ scale, int n) {
    const int lane = threadIdx.x & 63;
    const int wave = threadIdx.x >> 6;
    const int gw = blockIdx.x * 4 + wave;
    const int nw = gridDim.x * 4;
    for (int r = gw; r < n; r += nw) {
        const int beg = offs[r], end = offs[r + 1];
        float ax = 0.0f, ay = 0.0f;
        for (int j0 = beg; j0 < end; j0 += 64) {
            const int m = (end - j0 < 64) ? (end - j0) : 64;
            const int idx = (j0 + lane < end) ? srt[j0 + lane] : 0;
            for (int j = 0; j < m; ++j) {
                const int s = __shfl(idx, j);
                const unsigned v = src[(size_t)s * 64 + lane];
                ax += __uint_as_float(v << 16);
                ay += __uint_as_float(v & 0xFFFF0000u);
            }
        }
        const float sc = scale[r];
        dst[(size_t)r * 64 + lane] = bf16pack2(ax * sc, ay * sc);
    }
}

// ---------------------------------------------------------------------------
// MFMA graph-conv layer: y = bf16( softmax(relu(x @ W + b)) * inv_out )
// IN_BF16=false: x is f32 [N,128] (nodes). IN_BF16=true: x is bf16 rows
// (pre-scaled by aggregate). 64-row tile/block, wave w owns cols [32w,32w+32).
// ---------------------------------------------------------------------------
template<bool IN_BF16>
__global__ __launch_bounds__(256)
void gc_mfma(const void* __restrict__ xv, const unsigned short* __restrict__ Wt,
             const float* __restrict__ bias, const float* __restrict__ inv_out,
             unsigned short* __restrict__ y, int nrows) {
    __shared__ unsigned short Xl[64 * 136];
    __shared__ float sred0[4][64];
    __shared__ float sred1[4][64];
    const int row0 = blockIdx.x * 64;
    if (IN_BF16) {
        const uint2* xs = (const uint2*)xv;          // row = 32 uint2
        for (int c = threadIdx.x; c < 64 * 32; c += 256) {
            int r = c >> 5, cu = c & 31;
            int grow = row0 + r;
            uint2 v = make_uint2(0u, 0u);
            if (grow < nrows) v = xs[(size_t)grow * 32 + cu];
            *((uint2*)&Xl[r * 136] + cu) = v;
        }
    } else {
        const float* x = (const float*)xv;
        for (int c = threadIdx.x; c < 64 * 32; c += 256) {
            int r = c >> 5, c4 = c & 31;
            int grow = row0 + r;
            float4 v = make_float4(0.f, 0.f, 0.f, 0.f);
            if (grow < nrows) v = *(const float4*)&x[(size_t)grow * 128 + c4 * 4];
            *(uint2*)&Xl[r * 136 + c4 * 4] = make_uint2(bf16pack2(v.x, v.y), bf16pack2(v.z, v.w));
        }
    }
    __syncthreads();

    const int lane = threadIdx.x & 63;
    const int w = threadIdx.x >> 6;
    const int q = lane >> 4;
    const int l16 = lane & 15;

    short8 bf[4][2];
    #pragma unroll
    for (int k0 = 0; k0 < 4; ++k0)
        #pragma unroll
        for (int nt = 0; nt < 2; ++nt) {
            int ncol = w * 32 + nt * 16 + l16;
            bf[k0][nt] = *(const short8*)&Wt[ncol * 128 + k0 * 32 + q * 8];
        }

    f32x4 acc[4][2] = {};
    #pragma unroll
    for (int k0 = 0; k0 < 4; ++k0) {
        #pragma unroll
        for (int m = 0; m < 4; ++m) {
            short8 a = *(const short8*)&Xl[(m * 16 + l16) * 136 + k0 * 32 + q * 8];
            acc[m][0] = __builtin_amdgcn_mfma_f32_16x16x32_bf16(a, bf[k0][0], acc[m][0], 0, 0, 0);
            acc[m][1] = __builtin_amdgcn_mfma_f32_16x16x32_bf16(a, bf[k0][1], acc[m][1], 0, 0, 0);
        }
    }

    // bias -> relu -> softmax over 128 cols -> *inv_out -> bf16
    const float bv0 = bias[w * 32 + l16];
    const float bv1 = bias[w * 32 + 16 + l16];
    float v[4][2][4];
    #pragma unroll
    for (int m = 0; m < 4; ++m)
        #pragma unroll
        for (int r = 0; r < 4; ++r) {
            v[m][0][r] = fmaxf(acc[m][0][r] + bv0, 0.0f);
            v[m][1][r] = fmaxf(acc[m][1][r] + bv1, 0.0f);
        }
    float t[4][4];
    #pragma unroll
    for (int m = 0; m < 4; ++m)
        #pragma unroll
        for (int r = 0; r < 4; ++r)
            t[m][r] = fmaxf(v[m][0][r], v[m][1][r]);
    #pragma unroll
    for (int off = 1; off < 16; off <<= 1)
        #pragma unroll
        for (int m = 0; m < 4; ++m)
            #pragma unroll
            for (int r = 0; r < 4; ++r)
                t[m][r] = fmaxf(t[m][r], __shfl_xor(t[m][r], off));
    if (l16 == 0) {
        #pragma unroll
        for (int m = 0; m < 4; ++m)
            #pragma unroll
            for (int r = 0; r < 4; ++r)
                sred0[w][m * 16 + q * 4 + r] = t[m][r];
    }
    __syncthreads();
    float M[4][4];
    #pragma unroll
    for (int m = 0; m < 4; ++m)
        #pragma unroll
        for (int r = 0; r < 4; ++r) {
            int row = m * 16 + q * 4 + r;
            M[m][r] = fmaxf(fmaxf(sred0[0][row], sred0[1][row]),
                            fmaxf(sred0[2][row], sred0[3][row]));
        }
    float s[4][4];
    #pragma unroll
    for (int m = 0; m < 4; ++m)
        #pragma unroll
        for (int r = 0; r < 4; ++r) {
            float e0 = __expf(v[m][0][r] - M[m][r]);
            float e1 = __expf(v[m][1][r] - M[m][r]);
            v[m][0][r] = e0; v[m][1][r] = e1;
            s[m][r] = e0 + e1;
        }
    #pragma unroll
    for (int off = 1; off < 16; off <<= 1)
        #pragma unroll
        for (int m = 0; m < 4; ++m)
            #pragma unroll
            for (int r = 0; r < 4; ++r)
                s[m][r] += __shfl_xor(s[m][r], off);
    if (l16 == 0) {
        #pragma unroll
        for (int m = 0; m < 4; ++m)
            #pragma unroll
            for (int r = 0; r < 4; ++r)
                sred1[w][m * 16 + q * 4 + r] = s[m][r];
    }
    __syncthreads();
    #pragma unroll
    for (int m = 0; m < 4; ++m)
        #pragma unroll
        for (int r = 0; r < 4; ++r) {
            int row = m * 16 + q * 4 + r;
            int grow = row0 + row;
            if (grow < nrows) {
                float S = sred1[0][row] + sred1[1][row] + sred1[2][row] + sred1[3][row];
                float sc = inv_out[grow] / S;
                unsigned short* yrow = &y[(size_t)grow * 128];
                yrow[w * 32 + l16]      = bf16r(v[m][0][r] * sc);
                yrow[w * 32 + 16 + l16] = bf16r(v[m][1][r] * sc);
            }
        }
}

// ---------------------------------------------------------------------------
// Fused heads: X = concat(h, nodes) [64 rows x 256 k]; h already bf16 and
// pre-scaled by inv_r. Waves 0,1 -> mu cols; 2,3 -> logsig2 cols.
// ---------------------------------------------------------------------------
__global__ __launch_bounds__(256)
void head_mfma(const unsigned short* __restrict__ h, const float* __restrict__ nodes,
               const unsigned short* __restrict__ Wt,
               const float* __restrict__ bmu, const float* __restrict__ bls,
               float* __restrict__ out, int nrows) {
    __shared__ unsigned short Xl[64 * 264];
    const int row0 = blockIdx.x * 64;
    // cols 0..127: h (bf16 copy)
    {
        const uint2* hs = (const uint2*)h;
        for (int c = threadIdx.x; c < 64 * 32; c += 256) {
            int r = c >> 5, cu = c & 31;
            int grow = row0 + r;
            uint2 v = make_uint2(0u, 0u);
            if (grow < nrows) v = hs[(size_t)grow * 32 + cu];
            *((uint2*)&Xl[r * 264] + cu) = v;
        }
    }
    // cols 128..255: nodes (f32 -> bf16)
    for (int c = threadIdx.x; c < 64 * 32; c += 256) {
        int r = c >> 5, c4 = c & 31;
        int grow = row0 + r;
        float4 v = make_float4(0.f, 0.f, 0.f, 0.f);
        if (grow < nrows) v = *(const float4*)&nodes[(size_t)grow * 128 + c4 * 4];
        *(uint2*)&Xl[r * 264 + 128 + c4 * 4] = make_uint2(bf16pack2(v.x, v.y), bf16pack2(v.z, v.w));
    }
    __syncthreads();

    const int lane = threadIdx.x & 63;
    const int w = threadIdx.x >> 6;
    const int q = lane >> 4;
    const int l16 = lane & 15;

    short8 bf[8][2];
    #pragma unroll
    for (int k0 = 0; k0 < 8; ++k0)
        #pragma unroll
        for (int nt = 0; nt < 2; ++nt) {
            int ncol = w * 32 + nt * 16 + l16;
            bf[k0][nt] = *(const short8*)&Wt[ncol * 256 + k0 * 32 + q * 8];
        }

    f32x4 acc[4][2] = {};
    #pragma unroll
    for (int k0 = 0; k0 < 8; ++k0) {
        #pragma unroll
        for (int m = 0; m < 4; ++m) {
            short8 a = *(const short8*)&Xl[(m * 16 + l16) * 264 + k0 * 32 + q * 8];
            acc[m][0] = __builtin_amdgcn_mfma_f32_16x16x32_bf16(a, bf[k0][0], acc[m][0], 0, 0, 0);
            acc[m][1] = __builtin_amdgcn_mfma_f32_16x16x32_bf16(a, bf[k0][1], acc[m][1], 0, 0, 0);
        }
    }

    const float* bb = (w < 2) ? bmu : bls;
    float* ob = (w < 2) ? out : out + (size_t)nrows * 64;
    const int c0 = (w & 1) * 32 + l16;
    const int c1 = c0 + 16;
    const float b0v = bb[c0], b1v = bb[c1];
    #pragma unroll
    for (int m = 0; m < 4; ++m)
        #pragma unroll
        for (int r = 0; r < 4; ++r) {
            int grow = row0 + m * 16 + q * 4 + r;
            if (grow < nrows) {
                ob[(size_t)grow * 64 + c0] = acc[m][0][r] + b0v;
                ob[(size_t)grow * 64 + c1] = acc[m][1][r] + b1v;
            }
        }
}

extern "C" void kernel_launch(void* const* d_in, const int* in_sizes, int n_in,
                              void* d_out, int out_size, void* d_ws, size_t ws_size,
                              hipStream_t stream) {
    const float* nodes     = (const float*)d_in[0];
    const int*   senders   = (const int*)d_in[1];
    const int*   receivers = (const int*)d_in[2];
    const float* W0  = (const float*)d_in[3];
    const float* b0  = (const float*)d_in[4];
    const float* W1  = (const float*)d_in[5];
    const float* b1  = (const float*)d_in[6];
    const float* Wmu = (const float*)d_in[7];
    const float* bmu = (const float*)d_in[8];
    const float* Wls = (const float*)d_in[9];
    const float* bls = (const float*)d_in[10];
    float* out = (float*)d_out;

    const int N = N_NODES;
    const int E = N_EDGES;
    const int NB = (N + 255) / 256;      // scan blocks
    const int NT = (N + 63) / 64;        // 64-row GEMM tiles

    // ws: inv_s[N] f32 | inv_r[N] f32 | buf0[N*128] bf16 | buf1[N*128] bf16 | weights
    float* inv_s = (float*)d_ws;
    float* inv_r = inv_s + N;
    unsigned short* buf0 = (unsigned short*)(inv_r + N);
    unsigned short* buf1 = buf0 + (size_t)N * 128;
    unsigned short* w0t  = buf1 + (size_t)N * 128;
    unsigned short* w1t  = w0t + 128 * 128;
    unsigned short* wht  = w1t + 128 * 128;

    // sort metadata in d_out (scratch until heads write it): offs[N+1] | srt[E]
    int* offs = (int*)d_out;
    int* srt  = offs + (N + 1);

    // setup-only temps alias buf0 (dead before layer-1 writes buf0)
    int* cnt_s  = (int*)buf0;
    int* cnt_r  = cnt_s + N;
    int* cursor = cnt_r + N;
    int* bsum   = cursor + N;

    // --- weight prep (bf16 transposed) ---
    prep_wt128<<<64, 256, 0, stream>>>(W0, w0t);
    prep_wt128<<<64, 256, 0, stream>>>(W1, w1t);
    prep_wht<<<128, 256, 0, stream>>>(Wmu, Wls, wht);

    // --- degrees + counting sort of edges by receiver ---
    hipMemsetAsync(cnt_s, 0, 2ull * N * sizeof(int), stream);
    hist_kernel<<<(E + 255) / 256, 256, 0, stream>>>(senders, receivers, cnt_s, cnt_r, E);
    scan1_kernel<<<NB, 256, 0, stream>>>(cnt_r, offs, bsum, N);
    scan2_kernel<<<1, 512, 0, stream>>>(bsum, NB);
    scan3_kernel<<<NB, 256, 0, stream>>>(offs, bsum, cursor, cnt_s, cnt_r, inv_s, inv_r, N, E);
    reorder_kernel<<<(E + 255) / 256, 256, 0, stream>>>(senders, receivers, cursor, srt, E);

    // --- layer 1 ---
    gc_mfma<false><<<NT, 256, 0, stream>>>(nodes, w0t, b0, inv_s, buf0, N);
    aggregate_kernel<<<4096, 256, 0, stream>>>((const unsigned*)buf0, (unsigned*)buf1,
                                               offs, srt, inv_r, N);

    // --- layer 2 (input pre-scaled bf16) ---
    gc_mfma<true><<<NT, 256, 0, stream>>>(buf1, w1t, b1, inv_s, buf0, N);
    aggregate_kernel<<<4096, 256, 0, stream>>>((const unsigned*)buf0, (unsigned*)buf1,
                                               offs, srt, inv_r, N);

    // --- fused heads: out = [mu | logsig2] ---
    head_mfma<<<NT, 256, 0, stream>>>(buf1, nodes, wht, bmu, bls, out, N);
}

// Round 5
// 354.974 us; speedup vs baseline: 9.6837x; 1.1335x over previous
//
#include <hip/hip_runtime.h>

#define N_NODES 100000
#define N_EDGES 600000

typedef __attribute__((ext_vector_type(8))) short short8;   // 8 bf16 (4 VGPRs)
typedef __attribute__((ext_vector_type(4))) float f32x4;    // MFMA accumulator

// round-to-nearest-even f32 -> bf16
__device__ inline unsigned short bf16r(float x) {
    unsigned u = __float_as_uint(x);
    return (unsigned short)((u + 0x7FFFu + ((u >> 16) & 1u)) >> 16);
}
__device__ inline unsigned bf16pack2(float x, float y) {
    unsigned ux = __float_as_uint(x), uy = __float_as_uint(y);
    ux = (ux + 0x7FFFu + ((ux >> 16) & 1u)) >> 16;
    uy = (uy + 0x7FFFu + ((uy >> 16) & 1u)) >> 16;
    return ux | (uy << 16);
}

// ---------------------------------------------------------------------------
// Fused weight prep: w0t/w1t = transposed bf16 of W0/W1 (128x128);
// wht[n][k], n<64 from Wmu, n>=64 from Wls (128 n x 256 k).
// ---------------------------------------------------------------------------
__global__ void prep_weights(const float* __restrict__ W0, const float* __restrict__ W1,
                             const float* __restrict__ Wmu, const float* __restrict__ Wls,
                             unsigned short* __restrict__ w0t, unsigned short* __restrict__ w1t,
                             unsigned short* __restrict__ wht) {
    int i = blockIdx.x * 256 + threadIdx.x;   // 0 .. 65535
    if (i < 16384) {
        int nn = i >> 7, k = i & 127;
        w0t[i] = bf16r(W0[k * 128 + nn]);
    } else if (i < 32768) {
        int j = i - 16384;
        int nn = j >> 7, k = j & 127;
        w1t[j] = bf16r(W1[k * 128 + nn]);
    } else {
        int j = i - 32768;
        int nn = j >> 8, k = j & 255;
        float v = (nn < 64) ? Wmu[k * 64 + nn] : Wls[k * 64 + (nn - 64)];
        wht[j] = bf16r(v);
    }
}

// ---------------------------------------------------------------------------
// Histogram / scan / reorder (counting sort of edges by receiver)
// ---------------------------------------------------------------------------
__global__ void hist_kernel(const int* __restrict__ senders,
                            const int* __restrict__ receivers,
                            int* __restrict__ cnt_s, int* __restrict__ cnt_r, int nE) {
    int e = blockIdx.x * blockDim.x + threadIdx.x;
    if (e < nE) {
        atomicAdd(&cnt_s[senders[e]], 1);
        atomicAdd(&cnt_r[receivers[e]], 1);
    }
}

__global__ void scan1_kernel(const int* __restrict__ cnt, int* __restrict__ offs,
                             int* __restrict__ bsum, int n) {
    __shared__ int a[256], b[256];
    const int t = threadIdx.x;
    const int i = blockIdx.x * 256 + t;
    const int v = (i < n) ? cnt[i] : 0;
    a[t] = v;
    __syncthreads();
    int* pin = a; int* pout = b;
    #pragma unroll
    for (int off = 1; off < 256; off <<= 1) {
        pout[t] = pin[t] + ((t >= off) ? pin[t - off] : 0);
        __syncthreads();
        int* tmp = pin; pin = pout; pout = tmp;
    }
    if (i < n) offs[i] = pin[t] - v;
    if (t == 255) bsum[blockIdx.x] = pin[255];
}

__global__ void scan2_kernel(int* __restrict__ bsum, int nb) {
    __shared__ int a[512], b[512];
    const int t = threadIdx.x;
    const int v = (t < nb) ? bsum[t] : 0;
    a[t] = v;
    __syncthreads();
    int* pin = a; int* pout = b;
    #pragma unroll
    for (int off = 1; off < 512; off <<= 1) {
        pout[t] = pin[t] + ((t >= off) ? pin[t - off] : 0);
        __syncthreads();
        int* tmp = pin; pin = pout; pout = tmp;
    }
    if (t < nb) bsum[t] = pin[t] - v;
}

// finalize offsets + cursor + rsqrt degree factors (fused)
__global__ void scan3_kernel(int* __restrict__ offs, const int* __restrict__ bsum,
                             int* __restrict__ cursor,
                             const int* __restrict__ cs, const int* __restrict__ cr,
                             float* __restrict__ inv_s, float* __restrict__ inv_r,
                             int n, int total) {
    int i = blockIdx.x * 256 + threadIdx.x;
    if (i < n) {
        int o = offs[i] + bsum[i >> 8];
        offs[i] = o;
        cursor[i] = o;
        inv_s[i] = rsqrtf(fmaxf((float)cs[i], 1.0f));
        inv_r[i] = rsqrtf(fmaxf((float)cr[i], 1.0f));
    }
    if (i == 0) offs[n] = total;
}

__global__ void reorder_kernel(const int* __restrict__ senders,
                               const int* __restrict__ receivers,
                               int* __restrict__ cursor, int* __restrict__ srt, int nE) {
    int e = blockIdx.x * blockDim.x + threadIdx.x;
    if (e < nE) {
        int pos = atomicAdd(&cursor[receivers[e]], 1);
        srt[pos] = senders[e];
    }
}

// ---------------------------------------------------------------------------
// dst[r] = bf16( scale[r] * sum over incoming edges of src[sender] )
// src/dst: bf16 rows of 128 cols = 16 uint4. Each wave processes 4 receivers
// concurrently in 16-lane groups; lane loads uint4 (16 B) per edge -> 4
// independent row-streams per VMEM instruction (4x MLP vs one-row-per-wave).
// ---------------------------------------------------------------------------
__global__ __launch_bounds__(256)
void aggregate_kernel(const uint4* __restrict__ src, uint4* __restrict__ dst,
                      const int* __restrict__ offs, const int* __restrict__ srt,
                      const float* __restrict__ scale, int n) {
    const int lane = threadIdx.x & 63;
    const int wave = threadIdx.x >> 6;
    const int grp  = lane >> 4;          // 0..3 (receiver group within wave)
    const int l16  = lane & 15;
    const int wid  = blockIdx.x * 4 + wave;      // wave index
    const int nwv  = gridDim.x * 4;              // total waves
    const unsigned grpbase = lane & 48;          // grp*16, for shfl source

    for (int rb = wid * 4; rb < n; rb += nwv * 4) {   // wave-uniform
        const int r = rb + grp;
        const bool valid = (r < n);
        int beg = 0, deg = 0;
        if (valid) { beg = offs[r]; deg = offs[r + 1] - beg; }
        float ax[8];
        #pragma unroll
        for (int k = 0; k < 8; ++k) ax[k] = 0.0f;

        for (int j0 = 0; ; j0 += 16) {
            const int rem = deg - j0;            // group-uniform
            int wm = rem;                        // wave max remaining
            wm = max(wm, __shfl_xor(wm, 16));
            wm = max(wm, __shfl_xor(wm, 32));
            if (wm <= 0) break;
            const int idx = (j0 + l16 < deg) ? srt[beg + j0 + l16] : 0;
            const int jmax = (wm < 16) ? wm : 16;
            for (int j = 0; j < jmax; ++j) {
                const int s = __shfl(idx, grpbase + j);
                if (j < rem) {
                    const uint4 v = src[(size_t)s * 16 + l16];
                    ax[0] += __uint_as_float(v.x << 16);
                    ax[1] += __uint_as_float(v.x & 0xFFFF0000u);
                    ax[2] += __uint_as_float(v.y << 16);
                    ax[3] += __uint_as_float(v.y & 0xFFFF0000u);
                    ax[4] += __uint_as_float(v.z << 16);
                    ax[5] += __uint_as_float(v.z & 0xFFFF0000u);
                    ax[6] += __uint_as_float(v.w << 16);
                    ax[7] += __uint_as_float(v.w & 0xFFFF0000u);
                }
            }
        }
        if (valid) {
            const float sc = scale[r];
            uint4 o;
            o.x = bf16pack2(ax[0] * sc, ax[1] * sc);
            o.y = bf16pack2(ax[2] * sc, ax[3] * sc);
            o.z = bf16pack2(ax[4] * sc, ax[5] * sc);
            o.w = bf16pack2(ax[6] * sc, ax[7] * sc);
            dst[(size_t)r * 16 + l16] = o;
        }
    }
}

// ---------------------------------------------------------------------------
// MFMA graph-conv layer: y = bf16( softmax(relu(x @ W + b)) * inv_out )
// IN_BF16=false: x is f32 [N,128] (nodes). IN_BF16=true: x is bf16 rows
// (pre-scaled by aggregate). 64-row tile/block, wave w owns cols [32w,32w+32).
// ---------------------------------------------------------------------------
template<bool IN_BF16>
__global__ __launch_bounds__(256)
void gc_mfma(const void* __restrict__ xv, const unsigned short* __restrict__ Wt,
             const float* __restrict__ bias, const float* __restrict__ inv_out,
             unsigned short* __restrict__ y, int nrows) {
    __shared__ unsigned short Xl[64 * 136];
    __shared__ float sred0[4][64];
    __shared__ float sred1[4][64];
    const int row0 = blockIdx.x * 64;
    if (IN_BF16) {
        const uint2* xs = (const uint2*)xv;          // row = 32 uint2
        for (int c = threadIdx.x; c < 64 * 32; c += 256) {
            int r = c >> 5, cu = c & 31;
            int grow = row0 + r;
            uint2 v = make_uint2(0u, 0u);
            if (grow < nrows) v = xs[(size_t)grow * 32 + cu];
            *((uint2*)&Xl[r * 136] + cu) = v;
        }
    } else {
        const float* x = (const float*)xv;
        for (int c = threadIdx.x; c < 64 * 32; c += 256) {
            int r = c >> 5, c4 = c & 31;
            int grow = row0 + r;
            float4 v = make_float4(0.f, 0.f, 0.f, 0.f);
            if (grow < nrows) v = *(const float4*)&x[(size_t)grow * 128 + c4 * 4];
            *(uint2*)&Xl[r * 136 + c4 * 4] = make_uint2(bf16pack2(v.x, v.y), bf16pack2(v.z, v.w));
        }
    }
    __syncthreads();

    const int lane = threadIdx.x & 63;
    const int w = threadIdx.x >> 6;
    const int q = lane >> 4;
    const int l16 = lane & 15;

    short8 bf[4][2];
    #pragma unroll
    for (int k0 = 0; k0 < 4; ++k0)
        #pragma unroll
        for (int nt = 0; nt < 2; ++nt) {
            int ncol = w * 32 + nt * 16 + l16;
            bf[k0][nt] = *(const short8*)&Wt[ncol * 128 + k0 * 32 + q * 8];
        }

    f32x4 acc[4][2] = {};
    #pragma unroll
    for (int k0 = 0; k0 < 4; ++k0) {
        #pragma unroll
        for (int m = 0; m < 4; ++m) {
            short8 a = *(const short8*)&Xl[(m * 16 + l16) * 136 + k0 * 32 + q * 8];
            acc[m][0] = __builtin_amdgcn_mfma_f32_16x16x32_bf16(a, bf[k0][0], acc[m][0], 0, 0, 0);
            acc[m][1] = __builtin_amdgcn_mfma_f32_16x16x32_bf16(a, bf[k0][1], acc[m][1], 0, 0, 0);
        }
    }

    // bias -> relu -> softmax over 128 cols -> *inv_out -> bf16
    const float bv0 = bias[w * 32 + l16];
    const float bv1 = bias[w * 32 + 16 + l16];
    float v[4][2][4];
    #pragma unroll
    for (int m = 0; m < 4; ++m)
        #pragma unroll
        for (int r = 0; r < 4; ++r) {
            v[m][0][r] = fmaxf(acc[m][0][r] + bv0, 0.0f);
            v[m][1][r] = fmaxf(acc[m][1][r] + bv1, 0.0f);
        }
    float t[4][4];
    #pragma unroll
    for (int m = 0; m < 4; ++m)
        #pragma unroll
        for (int r = 0; r < 4; ++r)
            t[m][r] = fmaxf(v[m][0][r], v[m][1][r]);
    #pragma unroll
    for (int off = 1; off < 16; off <<= 1)
        #pragma unroll
        for (int m = 0; m < 4; ++m)
            #pragma unroll
            for (int r = 0; r < 4; ++r)
                t[m][r] = fmaxf(t[m][r], __shfl_xor(t[m][r], off));
    if (l16 == 0) {
        #pragma unroll
        for (int m = 0; m < 4; ++m)
            #pragma unroll
            for (int r = 0; r < 4; ++r)
                sred0[w][m * 16 + q * 4 + r] = t[m][r];
    }
    __syncthreads();
    float M[4][4];
    #pragma unroll
    for (int m = 0; m < 4; ++m)
        #pragma unroll
        for (int r = 0; r < 4; ++r) {
            int row = m * 16 + q * 4 + r;
            M[m][r] = fmaxf(fmaxf(sred0[0][row], sred0[1][row]),
                            fmaxf(sred0[2][row], sred0[3][row]));
        }
    float s[4][4];
    #pragma unroll
    for (int m = 0; m < 4; ++m)
        #pragma unroll
        for (int r = 0; r < 4; ++r) {
            float e0 = __expf(v[m][0][r] - M[m][r]);
            float e1 = __expf(v[m][1][r] - M[m][r]);
            v[m][0][r] = e0; v[m][1][r] = e1;
            s[m][r] = e0 + e1;
        }
    #pragma unroll
    for (int off = 1; off < 16; off <<= 1)
        #pragma unroll
        for (int m = 0; m < 4; ++m)
            #pragma unroll
            for (int r = 0; r < 4; ++r)
                s[m][r] += __shfl_xor(s[m][r], off);
    if (l16 == 0) {
        #pragma unroll
        for (int m = 0; m < 4; ++m)
            #pragma unroll
            for (int r = 0; r < 4; ++r)
                sred1[w][m * 16 + q * 4 + r] = s[m][r];
    }
    __syncthreads();
    #pragma unroll
    for (int m = 0; m < 4; ++m)
        #pragma unroll
        for (int r = 0; r < 4; ++r) {
            int row = m * 16 + q * 4 + r;
            int grow = row0 + row;
            if (grow < nrows) {
                float S = sred1[0][row] + sred1[1][row] + sred1[2][row] + sred1[3][row];
                float sc = inv_out[grow] / S;
                unsigned short* yrow = &y[(size_t)grow * 128];
                yrow[w * 32 + l16]      = bf16r(v[m][0][r] * sc);
                yrow[w * 32 + 16 + l16] = bf16r(v[m][1][r] * sc);
            }
        }
}

// ---------------------------------------------------------------------------
// Fused heads: X = concat(h, nodes) [64 rows x 256 k]; h already bf16 and
// pre-scaled by inv_r. Waves 0,1 -> mu cols; 2,3 -> logsig2 cols.
// ---------------------------------------------------------------------------
__global__ __launch_bounds__(256)
void head_mfma(const unsigned short* __restrict__ h, const float* __restrict__ nodes,
               const unsigned short* __restrict__ Wt,
               const float* __restrict__ bmu, const float* __restrict__ bls,
               float* __restrict__ out, int nrows) {
    __shared__ unsigned short Xl[64 * 264];
    const int row0 = blockIdx.x * 64;
    {
        const uint2* hs = (const uint2*)h;
        for (int c = threadIdx.x; c < 64 * 32; c += 256) {
            int r = c >> 5, cu = c & 31;
            int grow = row0 + r;
            uint2 v = make_uint2(0u, 0u);
            if (grow < nrows) v = hs[(size_t)grow * 32 + cu];
            *((uint2*)&Xl[r * 264] + cu) = v;
        }
    }
    for (int c = threadIdx.x; c < 64 * 32; c += 256) {
        int r = c >> 5, c4 = c & 31;
        int grow = row0 + r;
        float4 v = make_float4(0.f, 0.f, 0.f, 0.f);
        if (grow < nrows) v = *(const float4*)&nodes[(size_t)grow * 128 + c4 * 4];
        *(uint2*)&Xl[r * 264 + 128 + c4 * 4] = make_uint2(bf16pack2(v.x, v.y), bf16pack2(v.z, v.w));
    }
    __syncthreads();

    const int lane = threadIdx.x & 63;
    const int w = threadIdx.x >> 6;
    const int q = lane >> 4;
    const int l16 = lane & 15;

    short8 bf[8][2];
    #pragma unroll
    for (int k0 = 0; k0 < 8; ++k0)
        #pragma unroll
        for (int nt = 0; nt < 2; ++nt) {
            int ncol = w * 32 + nt * 16 + l16;
            bf[k0][nt] = *(const short8*)&Wt[ncol * 256 + k0 * 32 + q * 8];
        }

    f32x4 acc[4][2] = {};
    #pragma unroll
    for (int k0 = 0; k0 < 8; ++k0) {
        #pragma unroll
        for (int m = 0; m < 4; ++m) {
            short8 a = *(const short8*)&Xl[(m * 16 + l16) * 264 + k0 * 32 + q * 8];
            acc[m][0] = __builtin_amdgcn_mfma_f32_16x16x32_bf16(a, bf[k0][0], acc[m][0], 0, 0, 0);
            acc[m][1] = __builtin_amdgcn_mfma_f32_16x16x32_bf16(a, bf[k0][1], acc[m][1], 0, 0, 0);
        }
    }

    const float* bb = (w < 2) ? bmu : bls;
    float* ob = (w < 2) ? out : out + (size_t)nrows * 64;
    const int c0 = (w & 1) * 32 + l16;
    const int c1 = c0 + 16;
    const float b0v = bb[c0], b1v = bb[c1];
    #pragma unroll
    for (int m = 0; m < 4; ++m)
        #pragma unroll
        for (int r = 0; r < 4; ++r) {
            int grow = row0 + m * 16 + q * 4 + r;
            if (grow < nrows) {
                ob[(size_t)grow * 64 + c0] = acc[m][0][r] + b0v;
                ob[(size_t)grow * 64 + c1] = acc[m][1][r] + b1v;
            }
        }
}

extern "C" void kernel_launch(void* const* d_in, const int* in_sizes, int n_in,
                              void* d_out, int out_size, void* d_ws, size_t ws_size,
                              hipStream_t stream) {
    const float* nodes     = (const float*)d_in[0];
    const int*   senders   = (const int*)d_in[1];
    const int*   receivers = (const int*)d_in[2];
    const float* W0  = (const float*)d_in[3];
    const float* b0  = (const float*)d_in[4];
    const float* W1  = (const float*)d_in[5];
    const float* b1  = (const float*)d_in[6];
    const float* Wmu = (const float*)d_in[7];
    const float* bmu = (const float*)d_in[8];
    const float* Wls = (const float*)d_in[9];
    const float* bls = (const float*)d_in[10];
    float* out = (float*)d_out;

    const int N = N_NODES;
    const int E = N_EDGES;
    const int NB = (N + 255) / 256;      // scan blocks
    const int NT = (N + 63) / 64;        // 64-row GEMM tiles

    // ws: inv_s[N] f32 | inv_r[N] f32 | buf0[N*128] bf16 | buf1[N*128] bf16 | weights
    float* inv_s = (float*)d_ws;
    float* inv_r = inv_s + N;
    unsigned short* buf0 = (unsigned short*)(inv_r + N);
    unsigned short* buf1 = buf0 + (size_t)N * 128;
    unsigned short* w0t  = buf1 + (size_t)N * 128;
    unsigned short* w1t  = w0t + 128 * 128;
    unsigned short* wht  = w1t + 128 * 128;

    // sort metadata in d_out (scratch until heads write it): offs[N+1] | srt[E]
    int* offs = (int*)d_out;
    int* srt  = offs + (N + 1);

    // setup-only temps alias buf0 (dead before layer-1 writes buf0)
    int* cnt_s  = (int*)buf0;
    int* cnt_r  = cnt_s + N;
    int* cursor = cnt_r + N;
    int* bsum   = cursor + N;

    // --- weight prep (bf16 transposed, one launch) ---
    prep_weights<<<256, 256, 0, stream>>>(W0, W1, Wmu, Wls, w0t, w1t, wht);

    // --- degrees + counting sort of edges by receiver ---
    hipMemsetAsync(cnt_s, 0, 2ull * N * sizeof(int), stream);
    hist_kernel<<<(E + 255) / 256, 256, 0, stream>>>(senders, receivers, cnt_s, cnt_r, E);
    scan1_kernel<<<NB, 256, 0, stream>>>(cnt_r, offs, bsum, N);
    scan2_kernel<<<1, 512, 0, stream>>>(bsum, NB);
    scan3_kernel<<<NB, 256, 0, stream>>>(offs, bsum, cursor, cnt_s, cnt_r, inv_s, inv_r, N, E);
    reorder_kernel<<<(E + 255) / 256, 256, 0, stream>>>(senders, receivers, cursor, srt, E);

    // --- layer 1 ---
    gc_mfma<false><<<NT, 256, 0, stream>>>(nodes, w0t, b0, inv_s, buf0, N);
    aggregate_kernel<<<2048, 256, 0, stream>>>((const uint4*)buf0, (uint4*)buf1,
                                               offs, srt, inv_r, N);

    // --- layer 2 (input pre-scaled bf16) ---
    gc_mfma<true><<<NT, 256, 0, stream>>>(buf1, w1t, b1, inv_s, buf0, N);
    aggregate_kernel<<<2048, 256, 0, stream>>>((const uint4*)buf0, (uint4*)buf1,
                                               offs, srt, inv_r, N);

    // --- fused heads: out = [mu | logsig2] ---
    head_mfma<<<NT, 256, 0, stream>>>(buf1, nodes, wht, bmu, bls, out, N);
}